// Round 1
// baseline (334.997 us; speedup 1.0000x reference)
//
#include <hip/hip_runtime.h>

#define N_NODES 50000
#define N_EDGES 800000
#define D_FEAT  64
#define BATCH   2

// One wave (64 lanes) per edge: lane d handles feature d for both batches.
// 4 edges per 256-thread block.
__global__ __launch_bounds__(256) void scatter_add_kernel(
    const float* __restrict__ state,        // [B, N, D]
    const int*   __restrict__ edge_index,   // [2, E] (int32 per harness contract)
    const float* __restrict__ weight,       // [E, B]
    float*       __restrict__ out)          // [B, N, D]
{
    const int e = blockIdx.x * 4 + (threadIdx.x >> 6);
    const int d = threadIdx.x & 63;
    if (e >= N_EDGES) return;

    const int src = edge_index[e];
    const int dst = edge_index[N_EDGES + e];

    const float w0 = weight[e * BATCH + 0];
    const float w1 = weight[e * BATCH + 1];

    const size_t plane = (size_t)N_NODES * D_FEAT;

    const float s0 = state[(size_t)src * D_FEAT + d];
    const float s1 = state[plane + (size_t)src * D_FEAT + d];

    atomicAdd(out + (size_t)dst * D_FEAT + d,          s0 * w0);
    atomicAdd(out + plane + (size_t)dst * D_FEAT + d,  s1 * w1);
}

extern "C" void kernel_launch(void* const* d_in, const int* in_sizes, int n_in,
                              void* d_out, int out_size, void* d_ws, size_t ws_size,
                              hipStream_t stream) {
    const float* state      = (const float*)d_in[0];
    const int*   edge_index = (const int*)d_in[1];
    const float* weight     = (const float*)d_in[2];
    float*       out        = (float*)d_out;

    // Harness poisons d_out once (0xAA) and never re-poisons between replays:
    // we must zero it ourselves every call.
    hipMemsetAsync(out, 0, (size_t)out_size * sizeof(float), stream);

    const int edges_per_block = 4;
    dim3 grid((N_EDGES + edges_per_block - 1) / edges_per_block);
    dim3 block(256);
    hipLaunchKernelGGL(scatter_add_kernel, grid, block, 0, stream,
                       state, edge_index, weight, out);
}

// Round 2
// 308.034 us; speedup vs baseline: 1.0875x; 1.0875x over previous
//
#include <hip/hip_runtime.h>

#define N_NODES 50000
#define N_EDGES 800000
#define D_FEAT  64
#define BATCH   2

// ---------------- workspace layout (bytes) ----------------
// off    : (N+1) int  @ 0
// cursor :  N    int  @ 200016   (holds counts during hist, cursors during scatter)
// srcs   :  E    int  @ 400032
// wts    :  E float2  @ 3600032
// total  : 10000032 bytes
#define WS_OFF_OFF 0
#define WS_CUR_OFF 200016
#define WS_SRC_OFF 400032
#define WS_WTS_OFF 3600032
#define WS_NEEDED  10000032ull

__global__ __launch_bounds__(256) void hist_kernel(const int* __restrict__ ei,
                                                   int* __restrict__ cnt) {
    int e = blockIdx.x * 256 + threadIdx.x;
    if (e < N_EDGES) atomicAdd(&cnt[ei[N_EDGES + e]], 1);
}

__global__ __launch_bounds__(1024) void scan_kernel(int* __restrict__ cursor,
                                                    int* __restrict__ off) {
    __shared__ int sums[1024];
    const int CHUNK = (N_NODES + 1023) / 1024; // 49
    const int tid = threadIdx.x;
    const int base = tid * CHUNK;

    int local = 0;
    for (int i = 0; i < CHUNK; ++i) {
        int idx = base + i;
        if (idx < N_NODES) local += cursor[idx];
    }
    sums[tid] = local;
    __syncthreads();
    // Hillis-Steele inclusive scan over 1024 partials
    for (int s = 1; s < 1024; s <<= 1) {
        int v = 0;
        if (tid >= s) v = sums[tid - s];
        __syncthreads();
        if (tid >= s) sums[tid] += v;
        __syncthreads();
    }
    int prefix = (tid > 0) ? sums[tid - 1] : 0;
    for (int i = 0; i < CHUNK; ++i) {
        int idx = base + i;
        if (idx < N_NODES) {
            int c = cursor[idx];
            off[idx] = prefix;
            cursor[idx] = prefix;   // scatter cursor starts at segment base
            prefix += c;
        }
    }
    if (tid == 1023) off[N_NODES] = sums[1023];
}

__global__ __launch_bounds__(256) void scatter_kernel(const int* __restrict__ ei,
                                                      const float2* __restrict__ w,
                                                      int* __restrict__ cursor,
                                                      int* __restrict__ srcs,
                                                      float2* __restrict__ wts) {
    int e = blockIdx.x * 256 + threadIdx.x;
    if (e >= N_EDGES) return;
    int dst = ei[N_EDGES + e];
    int pos = atomicAdd(&cursor[dst], 1);
    srcs[pos] = ei[e];
    wts[pos]  = w[e];   // weight is [E,2] contiguous -> one 8B load
}

// One wave (64 lanes) per node; lane d owns feature d for both batches.
__global__ __launch_bounds__(256) void gather_kernel(const float* __restrict__ state,
                                                     const int* __restrict__ off,
                                                     const int* __restrict__ srcs,
                                                     const float2* __restrict__ wts,
                                                     float* __restrict__ out) {
    const int n = blockIdx.x * 4 + (threadIdx.x >> 6);
    const int d = threadIdx.x & 63;
    if (n >= N_NODES) return;
    const size_t plane = (size_t)N_NODES * D_FEAT;

    const int j0 = off[n], j1 = off[n + 1];
    float acc0 = 0.f, acc1 = 0.f;
    for (int j = j0; j < j1; ++j) {
        const int s    = srcs[j];           // wave-uniform broadcast load
        const float2 w = wts[j];            // wave-uniform broadcast load
        acc0 += state[(size_t)s * D_FEAT + d]         * w.x;
        acc1 += state[plane + (size_t)s * D_FEAT + d] * w.y;
    }
    out[(size_t)n * D_FEAT + d]         = acc0;
    out[plane + (size_t)n * D_FEAT + d] = acc1;
}

// ---------------- fallback (ws too small): round-1 atomic kernel ----------------
__global__ __launch_bounds__(256) void scatter_add_kernel(
    const float* __restrict__ state, const int* __restrict__ edge_index,
    const float* __restrict__ weight, float* __restrict__ out) {
    const int e = blockIdx.x * 4 + (threadIdx.x >> 6);
    const int d = threadIdx.x & 63;
    if (e >= N_EDGES) return;
    const int src = edge_index[e];
    const int dst = edge_index[N_EDGES + e];
    const float w0 = weight[e * BATCH + 0];
    const float w1 = weight[e * BATCH + 1];
    const size_t plane = (size_t)N_NODES * D_FEAT;
    const float s0 = state[(size_t)src * D_FEAT + d];
    const float s1 = state[plane + (size_t)src * D_FEAT + d];
    atomicAdd(out + (size_t)dst * D_FEAT + d,         s0 * w0);
    atomicAdd(out + plane + (size_t)dst * D_FEAT + d, s1 * w1);
}

extern "C" void kernel_launch(void* const* d_in, const int* in_sizes, int n_in,
                              void* d_out, int out_size, void* d_ws, size_t ws_size,
                              hipStream_t stream) {
    const float* state      = (const float*)d_in[0];
    const int*   edge_index = (const int*)d_in[1];
    const float* weight     = (const float*)d_in[2];
    float*       out        = (float*)d_out;

    if (ws_size >= WS_NEEDED) {
        char* ws = (char*)d_ws;
        int*    off    = (int*)(ws + WS_OFF_OFF);
        int*    cursor = (int*)(ws + WS_CUR_OFF);
        int*    srcs   = (int*)(ws + WS_SRC_OFF);
        float2* wts    = (float2*)(ws + WS_WTS_OFF);

        hipMemsetAsync(cursor, 0, (size_t)N_NODES * sizeof(int), stream);

        dim3 eblk(256), egrd((N_EDGES + 255) / 256);
        hipLaunchKernelGGL(hist_kernel, egrd, eblk, 0, stream, edge_index, cursor);
        hipLaunchKernelGGL(scan_kernel, dim3(1), dim3(1024), 0, stream, cursor, off);
        hipLaunchKernelGGL(scatter_kernel, egrd, eblk, 0, stream,
                           edge_index, (const float2*)weight, cursor, srcs, wts);
        // gather fully overwrites out -> no memset needed
        hipLaunchKernelGGL(gather_kernel, dim3((N_NODES + 3) / 4), dim3(256), 0, stream,
                           state, off, srcs, wts, out);
    } else {
        hipMemsetAsync(out, 0, (size_t)out_size * sizeof(float), stream);
        hipLaunchKernelGGL(scatter_add_kernel, dim3((N_EDGES + 3) / 4), dim3(256), 0, stream,
                           state, edge_index, weight, out);
    }
}

// Round 3
// 167.802 us; speedup vs baseline: 1.9964x; 1.8357x over previous
//
#include <hip/hip_runtime.h>

#define N_NODES 50000
#define N_EDGES 800000
#define D_FEAT  64
#define BATCH   2

#define SCAN_BLK  1024
#define N_SBLK    ((N_NODES + SCAN_BLK - 1) / SCAN_BLK)   // 49

// ---------------- workspace layout (bytes) ----------------
// off    : (N+1) int  @ 0
// cursor :  N    int  @ 200016   (counts during hist, cursors during scatter)
// srcs   :  E    int  @ 400032   (first 128 ints double as bsum/boff pre-scatter)
// wts    :  E float2  @ 3600032
#define WS_OFF_OFF 0
#define WS_CUR_OFF 200016
#define WS_SRC_OFF 400032
#define WS_WTS_OFF 3600032
#define WS_NEEDED  10000032ull

__global__ __launch_bounds__(256) void hist_kernel(const int* __restrict__ ei,
                                                   int* __restrict__ cnt) {
    int e = blockIdx.x * 256 + threadIdx.x;
    if (e < N_EDGES) atomicAdd(&cnt[ei[N_EDGES + e]], 1);
}

// Per-block exclusive scan of counts -> off (local), block totals -> bsum.
__global__ __launch_bounds__(SCAN_BLK) void scan_blocks(const int* __restrict__ cnt,
                                                        int* __restrict__ loc,
                                                        int* __restrict__ bsum) {
    const int gid  = blockIdx.x * SCAN_BLK + threadIdx.x;
    const int wid  = threadIdx.x >> 6;
    const int lane = threadIdx.x & 63;
    int v = (gid < N_NODES) ? cnt[gid] : 0;

    // wave-inclusive scan
    int x = v;
    #pragma unroll
    for (int s = 1; s < 64; s <<= 1) {
        int t = __shfl_up(x, s, 64);
        if (lane >= s) x += t;
    }
    __shared__ int wsum[16];
    if (lane == 63) wsum[wid] = x;
    __syncthreads();
    if (wid == 0) {
        int y = (lane < 16) ? wsum[lane] : 0;
        #pragma unroll
        for (int s = 1; s < 16; s <<= 1) {
            int t = __shfl_up(y, s, 64);
            if (lane >= s) y += t;
        }
        if (lane < 16) wsum[lane] = y;
    }
    __syncthreads();
    const int woff = (wid > 0) ? wsum[wid - 1] : 0;
    const int incl = x + woff;
    if (gid < N_NODES) loc[gid] = incl - v;          // exclusive, block-local
    if (threadIdx.x == SCAN_BLK - 1) bsum[blockIdx.x] = incl;  // block total
}

// Scan the 49 block totals (single wave) -> boff (exclusive), total -> off[N].
__global__ __launch_bounds__(64) void scan_tops(const int* __restrict__ bsum,
                                                int* __restrict__ boff,
                                                int* __restrict__ off) {
    const int lane = threadIdx.x;
    int v = (lane < N_SBLK) ? bsum[lane] : 0;
    int x = v;
    #pragma unroll
    for (int s = 1; s < 64; s <<= 1) {
        int t = __shfl_up(x, s, 64);
        if (lane >= s) x += t;
    }
    if (lane < N_SBLK) boff[lane] = x - v;
    if (lane == 63) off[N_NODES] = x;                // grand total = N_EDGES
}

// off[gid] += boff[block]; cursor = off.
__global__ __launch_bounds__(SCAN_BLK) void scan_add(int* __restrict__ off,
                                                     const int* __restrict__ boff,
                                                     int* __restrict__ cursor) {
    const int gid = blockIdx.x * SCAN_BLK + threadIdx.x;
    if (gid < N_NODES) {
        int o = off[gid] + boff[blockIdx.x];
        off[gid]    = o;
        cursor[gid] = o;
    }
}

__global__ __launch_bounds__(256) void scatter_kernel(const int* __restrict__ ei,
                                                      const float2* __restrict__ w,
                                                      int* __restrict__ cursor,
                                                      int* __restrict__ srcs,
                                                      float2* __restrict__ wts) {
    int e = blockIdx.x * 256 + threadIdx.x;
    if (e >= N_EDGES) return;
    int dst = ei[N_EDGES + e];
    int pos = atomicAdd(&cursor[dst], 1);
    srcs[pos] = ei[e];
    wts[pos]  = w[e];
}

// One wave per node. Lanes cooperatively (coalesced) load up to 64 edge
// records, broadcast via shfl so all state-gather addresses are available
// early for pipelining.
__global__ __launch_bounds__(256) void gather_kernel(const float* __restrict__ state,
                                                     const int* __restrict__ off,
                                                     const int* __restrict__ srcs,
                                                     const float2* __restrict__ wts,
                                                     float* __restrict__ out) {
    const int n = blockIdx.x * 4 + (threadIdx.x >> 6);
    const int d = threadIdx.x & 63;
    if (n >= N_NODES) return;
    const size_t plane = (size_t)N_NODES * D_FEAT;

    const int j0 = off[n], j1 = off[n + 1];
    float acc0 = 0.f, acc1 = 0.f;
    for (int base = j0; base < j1; base += 64) {
        const int cnt = min(64, j1 - base);
        int    s_l = 0;
        float2 w_l = make_float2(0.f, 0.f);
        if (d < cnt) { s_l = srcs[base + d]; w_l = wts[base + d]; }
        for (int j = 0; j < cnt; ++j) {
            const int   s  = __shfl(s_l,   j, 64);
            const float wx = __shfl(w_l.x, j, 64);
            const float wy = __shfl(w_l.y, j, 64);
            acc0 += state[(size_t)s * D_FEAT + d]         * wx;
            acc1 += state[plane + (size_t)s * D_FEAT + d] * wy;
        }
    }
    out[(size_t)n * D_FEAT + d]         = acc0;
    out[plane + (size_t)n * D_FEAT + d] = acc1;
}

// ---------------- fallback (ws too small): round-1 atomic kernel ----------------
__global__ __launch_bounds__(256) void scatter_add_kernel(
    const float* __restrict__ state, const int* __restrict__ edge_index,
    const float* __restrict__ weight, float* __restrict__ out) {
    const int e = blockIdx.x * 4 + (threadIdx.x >> 6);
    const int d = threadIdx.x & 63;
    if (e >= N_EDGES) return;
    const int src = edge_index[e];
    const int dst = edge_index[N_EDGES + e];
    const float w0 = weight[e * BATCH + 0];
    const float w1 = weight[e * BATCH + 1];
    const size_t plane = (size_t)N_NODES * D_FEAT;
    const float s0 = state[(size_t)src * D_FEAT + d];
    const float s1 = state[plane + (size_t)src * D_FEAT + d];
    atomicAdd(out + (size_t)dst * D_FEAT + d,         s0 * w0);
    atomicAdd(out + plane + (size_t)dst * D_FEAT + d, s1 * w1);
}

extern "C" void kernel_launch(void* const* d_in, const int* in_sizes, int n_in,
                              void* d_out, int out_size, void* d_ws, size_t ws_size,
                              hipStream_t stream) {
    const float* state      = (const float*)d_in[0];
    const int*   edge_index = (const int*)d_in[1];
    const float* weight     = (const float*)d_in[2];
    float*       out        = (float*)d_out;

    if (ws_size >= WS_NEEDED) {
        char* ws = (char*)d_ws;
        int*    off    = (int*)(ws + WS_OFF_OFF);
        int*    cursor = (int*)(ws + WS_CUR_OFF);
        int*    srcs   = (int*)(ws + WS_SRC_OFF);
        float2* wts    = (float2*)(ws + WS_WTS_OFF);
        // bsum/boff live in the srcs area; scatter overwrites it afterwards.
        int* bsum = srcs;
        int* boff = srcs + 64;

        hipMemsetAsync(cursor, 0, (size_t)N_NODES * sizeof(int), stream);

        dim3 eblk(256), egrd((N_EDGES + 255) / 256);
        hipLaunchKernelGGL(hist_kernel, egrd, eblk, 0, stream, edge_index, cursor);
        hipLaunchKernelGGL(scan_blocks, dim3(N_SBLK), dim3(SCAN_BLK), 0, stream,
                           cursor, off, bsum);
        hipLaunchKernelGGL(scan_tops, dim3(1), dim3(64), 0, stream, bsum, boff, off);
        hipLaunchKernelGGL(scan_add, dim3(N_SBLK), dim3(SCAN_BLK), 0, stream,
                           off, boff, cursor);
        hipLaunchKernelGGL(scatter_kernel, egrd, eblk, 0, stream,
                           edge_index, (const float2*)weight, cursor, srcs, wts);
        hipLaunchKernelGGL(gather_kernel, dim3((N_NODES + 3) / 4), dim3(256), 0, stream,
                           state, off, srcs, wts, out);
    } else {
        hipMemsetAsync(out, 0, (size_t)out_size * sizeof(float), stream);
        hipLaunchKernelGGL(scatter_add_kernel, dim3((N_EDGES + 3) / 4), dim3(256), 0, stream,
                           state, edge_index, weight, out);
    }
}

// Round 4
// 158.911 us; speedup vs baseline: 2.1081x; 1.0559x over previous
//
#include <hip/hip_runtime.h>

#define N_NODES 50000
#define N_EDGES 800000
#define D_FEAT  64
#define BATCH   2

#define SCAN_BLK 1024
#define N_SBLK   ((N_NODES + SCAN_BLK - 1) / SCAN_BLK)   // 49

// ---------------- workspace layout (bytes) ----------------
// cursor : N ints    @ 0        (counts -> block-local excl scan -> cursors -> ends)
// bsum   : 49 ints   @ 200000
// boff   : 49 ints   @ 200256   (lives through gather!)
// recs   : E float4  @ 200512   {src_as_float, w0, w1, unused}
#define WS_CUR_OFF 0
#define WS_BSUM_OFF 200000
#define WS_BOFF_OFF 200256
#define WS_REC_OFF  200512
#define WS_NEEDED   (200512ull + (unsigned long long)N_EDGES * 16ull)

__global__ __launch_bounds__(256) void hist_kernel(const int* __restrict__ ei,
                                                   int* __restrict__ cnt) {
    int e = blockIdx.x * 256 + threadIdx.x;
    if (e < N_EDGES) atomicAdd(&cnt[ei[N_EDGES + e]], 1);
}

// In-place per-block exclusive scan of counts; block totals -> bsum.
__global__ __launch_bounds__(SCAN_BLK) void scan_blocks(int* __restrict__ cnt,
                                                        int* __restrict__ bsum) {
    const int gid  = blockIdx.x * SCAN_BLK + threadIdx.x;
    const int wid  = threadIdx.x >> 6;
    const int lane = threadIdx.x & 63;
    int v = (gid < N_NODES) ? cnt[gid] : 0;

    int x = v;
    #pragma unroll
    for (int s = 1; s < 64; s <<= 1) {
        int t = __shfl_up(x, s, 64);
        if (lane >= s) x += t;
    }
    __shared__ int wsum[16];
    if (lane == 63) wsum[wid] = x;
    __syncthreads();
    if (wid == 0) {
        int y = (lane < 16) ? wsum[lane] : 0;
        #pragma unroll
        for (int s = 1; s < 16; s <<= 1) {
            int t = __shfl_up(y, s, 64);
            if (lane >= s) y += t;
        }
        if (lane < 16) wsum[lane] = y;
    }
    __syncthreads();
    const int woff = (wid > 0) ? wsum[wid - 1] : 0;
    const int incl = x + woff;
    if (gid < N_NODES) cnt[gid] = incl - v;                      // block-local exclusive
    if (threadIdx.x == SCAN_BLK - 1) bsum[blockIdx.x] = incl;    // block total
}

// Exclusive scan of 49 block totals (one wave).
__global__ __launch_bounds__(64) void scan_tops(const int* __restrict__ bsum,
                                                int* __restrict__ boff) {
    const int lane = threadIdx.x;
    int v = (lane < N_SBLK) ? bsum[lane] : 0;
    int x = v;
    #pragma unroll
    for (int s = 1; s < 64; s <<= 1) {
        int t = __shfl_up(x, s, 64);
        if (lane >= s) x += t;
    }
    if (lane < N_SBLK) boff[lane] = x - v;
}

// Counting-sort scatter: one packed 16-B record per edge.
__global__ __launch_bounds__(256) void scatter_pack(const int* __restrict__ ei,
                                                    const float2* __restrict__ w,
                                                    int* __restrict__ cursor,
                                                    const int* __restrict__ boff,
                                                    float4* __restrict__ recs) {
    int e = blockIdx.x * 256 + threadIdx.x;
    if (e >= N_EDGES) return;
    const int src = ei[e];
    const int dst = ei[N_EDGES + e];
    const float2 wv = w[e];
    const int pos = atomicAdd(&cursor[dst], 1) + boff[dst >> 10];
    recs[pos] = make_float4(__int_as_float(src), wv.x, wv.y, 0.f);
}

// One wave per node; lanes cooperatively load 64 packed records, broadcast
// via shfl; edge loop hand-unrolled x4 for memory-level parallelism.
__global__ __launch_bounds__(256) void gather_kernel(const float* __restrict__ state,
                                                     const int* __restrict__ cursor,
                                                     const int* __restrict__ boff,
                                                     const float4* __restrict__ recs,
                                                     float* __restrict__ out) {
    const int n = blockIdx.x * 4 + (threadIdx.x >> 6);
    const int d = threadIdx.x & 63;
    if (n >= N_NODES) return;
    const size_t plane = (size_t)N_NODES * D_FEAT;

    // cursor[m] (post-scatter) = local_start[m]+count[m]; +boff = global end[m]
    const int j0 = (n > 0) ? (cursor[n - 1] + boff[(n - 1) >> 10]) : 0;
    const int j1 = cursor[n] + boff[n >> 10];

    float a0 = 0.f, a1 = 0.f, b0 = 0.f, b1 = 0.f;
    for (int base = j0; base < j1; base += 64) {
        const int cnt = min(64, j1 - base);
        float4 r = make_float4(0.f, 0.f, 0.f, 0.f);
        if (d < cnt) r = recs[base + d];

        int j = 0;
        for (; j + 4 <= cnt; j += 4) {
            const int   s0 = __shfl(__float_as_int(r.x), j + 0, 64);
            const float x0 = __shfl(r.y, j + 0, 64);
            const float y0 = __shfl(r.z, j + 0, 64);
            const int   s1 = __shfl(__float_as_int(r.x), j + 1, 64);
            const float x1 = __shfl(r.y, j + 1, 64);
            const float y1 = __shfl(r.z, j + 1, 64);
            const int   s2 = __shfl(__float_as_int(r.x), j + 2, 64);
            const float x2 = __shfl(r.y, j + 2, 64);
            const float y2 = __shfl(r.z, j + 2, 64);
            const int   s3 = __shfl(__float_as_int(r.x), j + 3, 64);
            const float x3 = __shfl(r.y, j + 3, 64);
            const float y3 = __shfl(r.z, j + 3, 64);

            const float v00 = state[(size_t)s0 * D_FEAT + d];
            const float v01 = state[plane + (size_t)s0 * D_FEAT + d];
            const float v10 = state[(size_t)s1 * D_FEAT + d];
            const float v11 = state[plane + (size_t)s1 * D_FEAT + d];
            const float v20 = state[(size_t)s2 * D_FEAT + d];
            const float v21 = state[plane + (size_t)s2 * D_FEAT + d];
            const float v30 = state[(size_t)s3 * D_FEAT + d];
            const float v31 = state[plane + (size_t)s3 * D_FEAT + d];

            a0 += v00 * x0; a1 += v01 * y0;
            b0 += v10 * x1; b1 += v11 * y1;
            a0 += v20 * x2; a1 += v21 * y2;
            b0 += v30 * x3; b1 += v31 * y3;
        }
        for (; j < cnt; ++j) {
            const int   s  = __shfl(__float_as_int(r.x), j, 64);
            const float wx = __shfl(r.y, j, 64);
            const float wy = __shfl(r.z, j, 64);
            a0 += state[(size_t)s * D_FEAT + d]         * wx;
            a1 += state[plane + (size_t)s * D_FEAT + d] * wy;
        }
    }
    out[(size_t)n * D_FEAT + d]         = a0 + b0;
    out[plane + (size_t)n * D_FEAT + d] = a1 + b1;
}

// ---------------- fallback (ws too small): round-1 atomic kernel ----------------
__global__ __launch_bounds__(256) void scatter_add_kernel(
    const float* __restrict__ state, const int* __restrict__ edge_index,
    const float* __restrict__ weight, float* __restrict__ out) {
    const int e = blockIdx.x * 4 + (threadIdx.x >> 6);
    const int d = threadIdx.x & 63;
    if (e >= N_EDGES) return;
    const int src = edge_index[e];
    const int dst = edge_index[N_EDGES + e];
    const float w0 = weight[e * BATCH + 0];
    const float w1 = weight[e * BATCH + 1];
    const size_t plane = (size_t)N_NODES * D_FEAT;
    const float s0 = state[(size_t)src * D_FEAT + d];
    const float s1 = state[plane + (size_t)src * D_FEAT + d];
    atomicAdd(out + (size_t)dst * D_FEAT + d,         s0 * w0);
    atomicAdd(out + plane + (size_t)dst * D_FEAT + d, s1 * w1);
}

extern "C" void kernel_launch(void* const* d_in, const int* in_sizes, int n_in,
                              void* d_out, int out_size, void* d_ws, size_t ws_size,
                              hipStream_t stream) {
    const float* state      = (const float*)d_in[0];
    const int*   edge_index = (const int*)d_in[1];
    const float* weight     = (const float*)d_in[2];
    float*       out        = (float*)d_out;

    if (ws_size >= WS_NEEDED) {
        char* ws = (char*)d_ws;
        int*    cursor = (int*)(ws + WS_CUR_OFF);
        int*    bsum   = (int*)(ws + WS_BSUM_OFF);
        int*    boff   = (int*)(ws + WS_BOFF_OFF);
        float4* recs   = (float4*)(ws + WS_REC_OFF);

        hipMemsetAsync(cursor, 0, (size_t)N_NODES * sizeof(int), stream);

        dim3 eblk(256), egrd((N_EDGES + 255) / 256);
        hipLaunchKernelGGL(hist_kernel, egrd, eblk, 0, stream, edge_index, cursor);
        hipLaunchKernelGGL(scan_blocks, dim3(N_SBLK), dim3(SCAN_BLK), 0, stream,
                           cursor, bsum);
        hipLaunchKernelGGL(scan_tops, dim3(1), dim3(64), 0, stream, bsum, boff);
        hipLaunchKernelGGL(scatter_pack, egrd, eblk, 0, stream,
                           edge_index, (const float2*)weight, cursor, boff, recs);
        hipLaunchKernelGGL(gather_kernel, dim3((N_NODES + 3) / 4), dim3(256), 0, stream,
                           state, cursor, boff, recs, out);
    } else {
        hipMemsetAsync(out, 0, (size_t)out_size * sizeof(float), stream);
        hipLaunchKernelGGL(scatter_add_kernel, dim3((N_EDGES + 3) / 4), dim3(256), 0, stream,
                           state, edge_index, weight, out);
    }
}

// Round 6
// 158.666 us; speedup vs baseline: 2.1113x; 1.0015x over previous
//
#include <hip/hip_runtime.h>

#define N_NODES 50000
#define N_EDGES 800000
#define D_FEAT  64
#define BATCH   2

#define SCAN_BLK 1024
#define N_SBLK   ((N_NODES + SCAN_BLK - 1) / SCAN_BLK)   // 49

typedef float nfloat2 __attribute__((ext_vector_type(2)));
typedef float nfloat4 __attribute__((ext_vector_type(4)));

// ---------------- workspace layout (bytes) ----------------
// cursor : N ints    @ 0        (counts -> block-local excl scan -> cursors -> ends)
// bsum   : 49 ints   @ 200000
// boff   : 49 ints   @ 200256   (lives through gather!)
// recs   : E nfloat4 @ 200512   {src_as_float, w0, w1, unused}
#define WS_CUR_OFF  0
#define WS_BSUM_OFF 200000
#define WS_BOFF_OFF 200256
#define WS_REC_OFF  200512
#define WS_NEEDED   (200512ull + (unsigned long long)N_EDGES * 16ull)

__global__ __launch_bounds__(256) void hist_kernel(const int* __restrict__ ei,
                                                   int* __restrict__ cnt) {
    int e = blockIdx.x * 256 + threadIdx.x;
    if (e < N_EDGES) atomicAdd(&cnt[__builtin_nontemporal_load(ei + N_EDGES + e)], 1);
}

// In-place per-block exclusive scan of counts; block totals -> bsum.
__global__ __launch_bounds__(SCAN_BLK) void scan_blocks(int* __restrict__ cnt,
                                                        int* __restrict__ bsum) {
    const int gid  = blockIdx.x * SCAN_BLK + threadIdx.x;
    const int wid  = threadIdx.x >> 6;
    const int lane = threadIdx.x & 63;
    int v = (gid < N_NODES) ? cnt[gid] : 0;

    int x = v;
    #pragma unroll
    for (int s = 1; s < 64; s <<= 1) {
        int t = __shfl_up(x, s, 64);
        if (lane >= s) x += t;
    }
    __shared__ int wsum[16];
    if (lane == 63) wsum[wid] = x;
    __syncthreads();
    if (wid == 0) {
        int y = (lane < 16) ? wsum[lane] : 0;
        #pragma unroll
        for (int s = 1; s < 16; s <<= 1) {
            int t = __shfl_up(y, s, 64);
            if (lane >= s) y += t;
        }
        if (lane < 16) wsum[lane] = y;
    }
    __syncthreads();
    const int woff = (wid > 0) ? wsum[wid - 1] : 0;
    const int incl = x + woff;
    if (gid < N_NODES) cnt[gid] = incl - v;                      // block-local exclusive
    if (threadIdx.x == SCAN_BLK - 1) bsum[blockIdx.x] = incl;    // block total
}

// Exclusive scan of 49 block totals (one wave).
__global__ __launch_bounds__(64) void scan_tops(const int* __restrict__ bsum,
                                                int* __restrict__ boff) {
    const int lane = threadIdx.x;
    int v = (lane < N_SBLK) ? bsum[lane] : 0;
    int x = v;
    #pragma unroll
    for (int s = 1; s < 64; s <<= 1) {
        int t = __shfl_up(x, s, 64);
        if (lane >= s) x += t;
    }
    if (lane < N_SBLK) boff[lane] = x - v;
}

// Counting-sort scatter: one packed 16-B record per edge.
__global__ __launch_bounds__(256) void scatter_pack(const int* __restrict__ ei,
                                                    const float* __restrict__ w,
                                                    int* __restrict__ cursor,
                                                    const int* __restrict__ boff,
                                                    nfloat4* __restrict__ recs) {
    int e = blockIdx.x * 256 + threadIdx.x;
    if (e >= N_EDGES) return;
    const int src = __builtin_nontemporal_load(ei + e);
    const int dst = __builtin_nontemporal_load(ei + N_EDGES + e);
    const nfloat2 wv = __builtin_nontemporal_load((const nfloat2*)(w + 2 * e));
    const int pos = atomicAdd(&cursor[dst], 1) + boff[dst >> 10];
    nfloat4 rec;
    rec.x = __int_as_float(src);
    rec.y = wv.x;
    rec.z = wv.y;
    rec.w = 0.f;
    recs[pos] = rec;
}

// One wave per node; lanes cooperatively load 64 packed records, broadcast
// via shfl; edge loop hand-unrolled x8 -> 16 state loads in flight.
__global__ __launch_bounds__(256) void gather_kernel(const float* __restrict__ state,
                                                     const int* __restrict__ cursor,
                                                     const int* __restrict__ boff,
                                                     const nfloat4* __restrict__ recs,
                                                     float* __restrict__ out) {
    const int n = blockIdx.x * 4 + (threadIdx.x >> 6);
    const int d = threadIdx.x & 63;
    if (n >= N_NODES) return;
    const size_t plane = (size_t)N_NODES * D_FEAT;

    // cursor[m] (post-scatter) = local_start[m]+count[m]; +boff = global end[m]
    const int j0 = (n > 0) ? (cursor[n - 1] + boff[(n - 1) >> 10]) : 0;
    const int j1 = cursor[n] + boff[n >> 10];

    float a0 = 0.f, a1 = 0.f;
    for (int base = j0; base < j1; base += 64) {
        const int cnt = min(64, j1 - base);
        nfloat4 r = (nfloat4)(0.f);
        if (d < cnt) r = __builtin_nontemporal_load(recs + base + d);

        int j = 0;
        for (; j + 8 <= cnt; j += 8) {
            int   s[8]; float wx[8], wy[8], v0[8], v1[8];
            #pragma unroll
            for (int u = 0; u < 8; ++u) {
                s[u]  = __shfl(__float_as_int(r.x), j + u, 64);
                wx[u] = __shfl(r.y, j + u, 64);
                wy[u] = __shfl(r.z, j + u, 64);
            }
            #pragma unroll
            for (int u = 0; u < 8; ++u) {
                v0[u] = state[(size_t)s[u] * D_FEAT + d];
                v1[u] = state[plane + (size_t)s[u] * D_FEAT + d];
            }
            #pragma unroll
            for (int u = 0; u < 8; ++u) {
                a0 += v0[u] * wx[u];
                a1 += v1[u] * wy[u];
            }
        }
        for (; j < cnt; ++j) {
            const int   s  = __shfl(__float_as_int(r.x), j, 64);
            const float wx = __shfl(r.y, j, 64);
            const float wy = __shfl(r.z, j, 64);
            a0 += state[(size_t)s * D_FEAT + d]         * wx;
            a1 += state[plane + (size_t)s * D_FEAT + d] * wy;
        }
    }
    __builtin_nontemporal_store(a0, out + (size_t)n * D_FEAT + d);
    __builtin_nontemporal_store(a1, out + plane + (size_t)n * D_FEAT + d);
}

// ---------------- fallback (ws too small): round-1 atomic kernel ----------------
__global__ __launch_bounds__(256) void scatter_add_kernel(
    const float* __restrict__ state, const int* __restrict__ edge_index,
    const float* __restrict__ weight, float* __restrict__ out) {
    const int e = blockIdx.x * 4 + (threadIdx.x >> 6);
    const int d = threadIdx.x & 63;
    if (e >= N_EDGES) return;
    const int src = edge_index[e];
    const int dst = edge_index[N_EDGES + e];
    const float w0 = weight[e * BATCH + 0];
    const float w1 = weight[e * BATCH + 1];
    const size_t plane = (size_t)N_NODES * D_FEAT;
    const float s0 = state[(size_t)src * D_FEAT + d];
    const float s1 = state[plane + (size_t)src * D_FEAT + d];
    atomicAdd(out + (size_t)dst * D_FEAT + d,         s0 * w0);
    atomicAdd(out + plane + (size_t)dst * D_FEAT + d, s1 * w1);
}

extern "C" void kernel_launch(void* const* d_in, const int* in_sizes, int n_in,
                              void* d_out, int out_size, void* d_ws, size_t ws_size,
                              hipStream_t stream) {
    const float* state      = (const float*)d_in[0];
    const int*   edge_index = (const int*)d_in[1];
    const float* weight     = (const float*)d_in[2];
    float*       out        = (float*)d_out;

    if (ws_size >= WS_NEEDED) {
        char* ws = (char*)d_ws;
        int*     cursor = (int*)(ws + WS_CUR_OFF);
        int*     bsum   = (int*)(ws + WS_BSUM_OFF);
        int*     boff   = (int*)(ws + WS_BOFF_OFF);
        nfloat4* recs   = (nfloat4*)(ws + WS_REC_OFF);

        (void)hipMemsetAsync(cursor, 0, (size_t)N_NODES * sizeof(int), stream);

        dim3 eblk(256), egrd((N_EDGES + 255) / 256);
        hipLaunchKernelGGL(hist_kernel, egrd, eblk, 0, stream, edge_index, cursor);
        hipLaunchKernelGGL(scan_blocks, dim3(N_SBLK), dim3(SCAN_BLK), 0, stream,
                           cursor, bsum);
        hipLaunchKernelGGL(scan_tops, dim3(1), dim3(64), 0, stream, bsum, boff);
        hipLaunchKernelGGL(scatter_pack, egrd, eblk, 0, stream,
                           edge_index, weight, cursor, boff, recs);
        hipLaunchKernelGGL(gather_kernel, dim3((N_NODES + 3) / 4), dim3(256), 0, stream,
                           state, cursor, boff, recs, out);
    } else {
        (void)hipMemsetAsync(out, 0, (size_t)out_size * sizeof(float), stream);
        hipLaunchKernelGGL(scatter_add_kernel, dim3((N_EDGES + 3) / 4), dim3(256), 0, stream,
                           state, edge_index, weight, out);
    }
}